// Round 15
// baseline (114.918 us; speedup 1.0000x reference)
//
#include <hip/hip_runtime.h>

#define NROW 4096
#define CH   256
#define MAXNNZ 128

typedef short  short8  __attribute__((ext_vector_type(8)));
typedef unsigned short ushort8 __attribute__((ext_vector_type(8)));
typedef float  f32x4   __attribute__((ext_vector_type(4)));

__device__ inline unsigned short f2bf(float f) {
  unsigned u = __float_as_uint(f);
  return (unsigned short)((u + 0x7fffu + ((u >> 16) & 1u)) >> 16);
}
__device__ inline float bf2f(unsigned short h) {
  return __uint_as_float((unsigned)h << 16);
}
__device__ inline int mbcnt64(unsigned long long m, int base) {
  int t = __builtin_amdgcn_mbcnt_lo((unsigned)m, (unsigned)base);
  return __builtin_amdgcn_mbcnt_hi((unsigned)(m >> 32), t);
}

// ---------------------------------------------------------------------------
// Pure CSR scan, one block per (mat,row), nt loads (fast path: 44us fused in
// r12; ~40us expected pure). Decoupled from the GEMM so the tail doesn't
// immediately follow the HBM burst (transient-penalty hypothesis).
__global__ __launch_bounds__(256) void scan_nt(
    const float* __restrict__ L0, const float* __restrict__ L1,
    const float* __restrict__ L2, int* __restrict__ idx,
    float* __restrict__ val, int* __restrict__ cnt) {
  __shared__ int   sj[4][MAXNNZ];
  __shared__ float sv[4][MAXNNZ];
  __shared__ int   scnt[4];
  const int cid = blockIdx.x;
  const int mat = cid >> 12, row = cid & 4095;
  const float* L = (mat == 0) ? L0 : (mat == 1) ? L1 : L2;
  const int wi = threadIdx.x >> 6, lane = threadIdx.x & 63;
  const f32x4* Lseg = (const f32x4*)(L + (size_t)row * NROW) + wi * 256;

  f32x4 v0 = __builtin_nontemporal_load(Lseg + lane);
  f32x4 v1 = __builtin_nontemporal_load(Lseg + 64 + lane);
  f32x4 v2 = __builtin_nontemporal_load(Lseg + 128 + lane);
  f32x4 v3 = __builtin_nontemporal_load(Lseg + 192 + lane);

  int base = 0;
#define PROCQ(q, cb) {                                                          \
    bool a0 = q[0] != 0.f, a1 = q[1] != 0.f, a2 = q[2] != 0.f, a3 = q[3] != 0.f; \
    unsigned long long b0 = __ballot(a0), b1 = __ballot(a1);                    \
    unsigned long long b2 = __ballot(a2), b3 = __ballot(a3);                    \
    int off = mbcnt64(b3, mbcnt64(b2, mbcnt64(b1, mbcnt64(b0, base))));         \
    if (a0) { if (off < MAXNNZ) { sj[wi][off] = (cb);     sv[wi][off] = q[0]; } ++off; } \
    if (a1) { if (off < MAXNNZ) { sj[wi][off] = (cb) + 1; sv[wi][off] = q[1]; } ++off; } \
    if (a2) { if (off < MAXNNZ) { sj[wi][off] = (cb) + 2; sv[wi][off] = q[2]; } ++off; } \
    if (a3) { if (off < MAXNNZ) { sj[wi][off] = (cb) + 3; sv[wi][off] = q[3]; } ++off; } \
    base += __popcll(b0) + __popcll(b1) + __popcll(b2) + __popcll(b3); }
  int colb = wi * 1024 + lane * 4;
  PROCQ(v0, colb)
  PROCQ(v1, colb + 256)
  PROCQ(v2, colb + 512)
  PROCQ(v3, colb + 768)
#undef PROCQ
  if (lane == 0) scnt[wi] = base < MAXNNZ ? base : MAXNNZ;
  __syncthreads();

  int c0 = scnt[0], c1 = scnt[1], c2 = scnt[2], c3 = scnt[3];
  int total = c0 + c1 + c2 + c3;
  if (total > MAXNNZ) total = MAXNNZ;
  size_t rbase = ((size_t)mat * NROW + row) * MAXNNZ;
  int t = threadIdx.x;
  if (t < total) {
    int s, o;
    if      (t < c0)           { s = 0; o = t; }
    else if (t < c0 + c1)      { s = 1; o = t - c0; }
    else if (t < c0 + c1 + c2) { s = 2; o = t - c0 - c1; }
    else                       { s = 3; o = t - c0 - c1 - c2; }
    idx[rbase + t] = sj[s][o];
    val[rbase + t] = sv[s][o];
  }
  if (t == 0) cnt[mat * NROW + row] = total;
}

// ---------------------------------------------------------------------------
// One dispatch converting x, Wirr_w, Wsol_w, Whar_w to bf16 (4 f32/thread).
// Runs AFTER the scan (part of the post-burst buffer window).
__global__ void cvt_all(const float* __restrict__ x, const float* __restrict__ Wi,
                        const float* __restrict__ Ws, const float* __restrict__ Wh,
                        unsigned short* __restrict__ xbf, unsigned short* __restrict__ Bbf) {
  int i = blockIdx.x * 256 + threadIdx.x;       // float4 index
  const float* src; unsigned short* dst; int o;
  if (i < 262144)        { src = x;  dst = xbf;          o = i; }
  else if (i < 294912)   { src = Wi; dst = Bbf;          o = i - 262144; }
  else if (i < 327680)   { src = Ws; dst = Bbf + 131072; o = i - 294912; }
  else                   { src = Wh; dst = Bbf + 262144; o = i - 327680; }
  float4 v = ((const float4*)src)[o];
  ushort4 u;
  u.x = f2bf(v.x); u.y = f2bf(v.y); u.z = f2bf(v.z); u.w = f2bf(v.w);
  ((ushort4*)dst)[o] = u;
}

// ---------------------------------------------------------------------------
// Standalone Y[4096][1280] = xbf @ Bbf^T, 64x64 tiles, BK=64 x4 stages,
// 16KB LDS. Compute-bound: doubles as the buffer between the scan's HBM
// burst and the cache-sensitive tail.
__global__ __launch_bounds__(256) void gemm_mfma(
    const unsigned short* __restrict__ A, const unsigned short* __restrict__ Bt,
    unsigned short* __restrict__ Y) {
  __shared__ __align__(16) unsigned short sA[64 * 64];
  __shared__ __align__(16) unsigned short sB[64 * 64];
  const int gid = blockIdx.x, tid = threadIdx.x;
  const int m0 = (gid & 63) * 64, n0 = (gid >> 6) * 64;
  const int wid = tid >> 6, lane = tid & 63;
  const int wr = wid >> 1, wc = wid & 1, lr = lane & 15, kg = lane >> 4;
  f32x4 acc[2][2] = {};
#pragma unroll
  for (int kh = 0; kh < 4; ++kh) {
    for (int c = 0; c < 2; ++c) {
      int chunk = c * 256 + tid;        // 0..511
      int r  = chunk >> 3;              // 8 x 16B chunks per 128B row
      int cb = (chunk & 7) * 16;
      int cbs = cb ^ ((r & 7) << 4);
      ushort8 va = *(const ushort8*)((const char*)A  + (size_t)(m0 + r) * 512 + kh * 128 + cb);
      *(ushort8*)((char*)sA + r * 128 + cbs) = va;
      ushort8 vb = *(const ushort8*)((const char*)Bt + (size_t)(n0 + r) * 512 + kh * 128 + cb);
      *(ushort8*)((char*)sB + r * 128 + cbs) = vb;
    }
    __syncthreads();
#pragma unroll
    for (int ks = 0; ks < 2; ++ks) {
      int kb = ks * 64 + kg * 16;
      short8 a0, a1, b0, b1;
      { int r = wr * 32 + lr;      a0 = *(const short8*)((const char*)sA + r * 128 + (kb ^ ((r & 7) << 4))); }
      { int r = wr * 32 + 16 + lr; a1 = *(const short8*)((const char*)sA + r * 128 + (kb ^ ((r & 7) << 4))); }
      { int r = wc * 32 + lr;      b0 = *(const short8*)((const char*)sB + r * 128 + (kb ^ ((r & 7) << 4))); }
      { int r = wc * 32 + 16 + lr; b1 = *(const short8*)((const char*)sB + r * 128 + (kb ^ ((r & 7) << 4))); }
      acc[0][0] = __builtin_amdgcn_mfma_f32_16x16x32_bf16(a0, b0, acc[0][0], 0, 0, 0);
      acc[0][1] = __builtin_amdgcn_mfma_f32_16x16x32_bf16(a0, b1, acc[0][1], 0, 0, 0);
      acc[1][0] = __builtin_amdgcn_mfma_f32_16x16x32_bf16(a1, b0, acc[1][0], 0, 0, 0);
      acc[1][1] = __builtin_amdgcn_mfma_f32_16x16x32_bf16(a1, b1, acc[1][1], 0, 0, 0);
    }
    __syncthreads();
  }
#pragma unroll
  for (int mi = 0; mi < 2; ++mi)
#pragma unroll
    for (int ni = 0; ni < 2; ++ni) {
      int col = n0 + wc * 32 + ni * 16 + lr;
#pragma unroll
      for (int r4 = 0; r4 < 4; ++r4) {
        int row = m0 + wr * 32 + mi * 16 + kg * 4 + r4;
        Y[(size_t)row * 1280 + col] = f2bf(acc[mi][ni][r4]);
      }
    }
}

// ---------------------------------------------------------------------------
// MERGED per-row kernel: sdv (att-dots on own row's Y[0..1023]) + BOTH
// spmm_add branches (U_d -> cols 0-255, U_s -> cols 512-767). Gathers read
// only cols 256-511 / 768-1023 (never written) -> no cross-block race.
__global__ __launch_bounds__(256) void spmm_sdv(
    const int* __restrict__ idx, const float* __restrict__ val,
    const int* __restrict__ cnt, const float* __restrict__ ai,
    const float* __restrict__ as_, const float* __restrict__ bi,
    const float* __restrict__ bs, unsigned short* __restrict__ Y,
    float* __restrict__ sdv) {
  int row = blockIdx.x, t = threadIdx.x, w = t >> 6, l = t & 63;
  __shared__ float satt[2048];
  __shared__ float red2[8];
  __shared__ float sbias[4];
  __shared__ int   sj0[MAXNNZ], sj1[MAXNNZ];
  __shared__ float sv0[MAXNNZ], sv1[MAXNNZ];
  __shared__ float part[4][256];

  for (int k = t; k < 1024; k += 256) { satt[k] = ai[k]; satt[1024 + k] = as_[k]; }
  {
    const float* av = (w & 2) ? as_ : ai;
    const float* bv = (w & 2) ? bs : bi;
    int off = (w & 1) * 512;
    float b = 0.f;
    for (int k = l; k < 512; k += 64) b += av[off + k] * bv[k];
    for (int o = 32; o; o >>= 1) b += __shfl_xor(b, o);
    if (l == 0) sbias[w] = b;
  }
  int n0 = cnt[row], n1 = cnt[NROW + row];
  if (t < n0) { sj0[t] = idx[(size_t)row * MAXNNZ + t];          sv0[t] = val[(size_t)row * MAXNNZ + t]; }
  if (t < n1) { sj1[t] = idx[((size_t)NROW + row) * MAXNNZ + t]; sv1[t] = val[((size_t)NROW + row) * MAXNNZ + t]; }
  ushort4 y4 = *(const ushort4*)(Y + (size_t)row * 1280 + 4 * t);   // own row, pre-overwrite
  __syncthreads();

  {
    int c0 = 4 * t;
    int aoff = (t < 128) ? 0 : 1024;
    int cc = c0 & 511;
    float sp = satt[aoff + cc]       * bf2f(y4.x) + satt[aoff + cc + 1]       * bf2f(y4.y)
             + satt[aoff + cc + 2]   * bf2f(y4.z) + satt[aoff + cc + 3]       * bf2f(y4.w);
    float dp = satt[aoff + 512 + cc] * bf2f(y4.x) + satt[aoff + 512 + cc + 1] * bf2f(y4.y)
             + satt[aoff + 512 + cc + 2] * bf2f(y4.z) + satt[aoff + 512 + cc + 3] * bf2f(y4.w);
    for (int o = 32; o; o >>= 1) { sp += __shfl_xor(sp, o); dp += __shfl_xor(dp, o); }
    if (l == 0) { red2[w * 2] = sp; red2[w * 2 + 1] = dp; }
  }

  float4 acc0 = {0.f, 0.f, 0.f, 0.f}, acc1 = {0.f, 0.f, 0.f, 0.f};
  for (int k = w; k < n0; k += 4) {
    ushort4 y = *(const ushort4*)(Y + (size_t)sj0[k] * 1280 + 256 + 4 * l);
    float a = sv0[k];
    acc0.x += a * bf2f(y.x); acc0.y += a * bf2f(y.y);
    acc0.z += a * bf2f(y.z); acc0.w += a * bf2f(y.w);
  }
  for (int k = w; k < n1; k += 4) {
    ushort4 y = *(const ushort4*)(Y + (size_t)sj1[k] * 1280 + 768 + 4 * l);
    float a = sv1[k];
    acc1.x += a * bf2f(y.x); acc1.y += a * bf2f(y.y);
    acc1.z += a * bf2f(y.z); acc1.w += a * bf2f(y.w);
  }
  ((float4*)part[w])[l] = acc0;
  __syncthreads();
  if (t == 0) {
    sdv[row]            = red2[0] + red2[2] + sbias[0];
    sdv[NROW + row]     = red2[1] + red2[3] + sbias[1];
    sdv[2 * NROW + row] = red2[4] + red2[6] + sbias[2];
    sdv[3 * NROW + row] = red2[5] + red2[7] + sbias[3];
  }
  if (t < 64) {
    unsigned short* yp = Y + (size_t)row * 1280 + 4 * t;
    ushort4 yb = *(const ushort4*)yp;
    ushort4 o;
    o.x = f2bf(bf2f(yb.x) + part[0][4 * t]     + part[1][4 * t]     + part[2][4 * t]     + part[3][4 * t]);
    o.y = f2bf(bf2f(yb.y) + part[0][4 * t + 1] + part[1][4 * t + 1] + part[2][4 * t + 1] + part[3][4 * t + 1]);
    o.z = f2bf(bf2f(yb.z) + part[0][4 * t + 2] + part[1][4 * t + 2] + part[2][4 * t + 2] + part[3][4 * t + 2]);
    o.w = f2bf(bf2f(yb.w) + part[0][4 * t + 3] + part[1][4 * t + 3] + part[2][4 * t + 3] + part[3][4 * t + 3]);
    *(ushort4*)yp = o;
  }
  __syncthreads();
  ((float4*)part[w])[l] = acc1;
  __syncthreads();
  if (t < 64) {
    unsigned short* yp = Y + (size_t)row * 1280 + 512 + 4 * t;
    ushort4 yb = *(const ushort4*)yp;
    ushort4 o;
    o.x = f2bf(bf2f(yb.x) + part[0][4 * t]     + part[1][4 * t]     + part[2][4 * t]     + part[3][4 * t]);
    o.y = f2bf(bf2f(yb.y) + part[0][4 * t + 1] + part[1][4 * t + 1] + part[2][4 * t + 1] + part[3][4 * t + 1]);
    o.z = f2bf(bf2f(yb.z) + part[0][4 * t + 2] + part[1][4 * t + 2] + part[2][4 * t + 2] + part[3][4 * t + 2]);
    o.w = f2bf(bf2f(yb.w) + part[0][4 * t + 3] + part[1][4 * t + 3] + part[2][4 * t + 3] + part[3][4 * t + 3]);
    *(ushort4*)yp = o;
  }
}

// ---------------------------------------------------------------------------
// Z[row] = alpha_d @ U_d + alpha_s @ U_s + P @ Yh + (all biases)
__global__ __launch_bounds__(256) void final_z(const int* __restrict__ idx,
                        const float* __restrict__ val, const int* __restrict__ cnt,
                        const float* __restrict__ sdv,
                        const unsigned short* __restrict__ Y,
                        const float* __restrict__ bi, const float* __restrict__ bs,
                        const float* __restrict__ bh, float* __restrict__ Z) {
  int row = blockIdx.x, t = threadIdx.x, w = t >> 6, l = t & 63;
  __shared__ float sa[MAXNNZ];
  __shared__ int   sj[MAXNNZ];
  __shared__ float red[4];
  __shared__ float part[4][256];
  float4 acc = {0.f, 0.f, 0.f, 0.f};

  for (int br = 0; br < 2; ++br) {
    size_t rbase = ((size_t)br * NROW + row) * MAXNNZ;
    int n = cnt[br * NROW + row];
    const float* srcv = sdv + (2 * br) * NROW;
    const float* dstv = sdv + (2 * br + 1) * NROW;
    float e = -1e30f;
    if (t < n) {
      int j = idx[rbase + t];
      sj[t] = j;
      float v = srcv[row] + dstv[j];
      e = v >= 0.f ? v : 0.01f * v;
    }
    float m = e;
    for (int o = 32; o; o >>= 1) m = fmaxf(m, __shfl_xor(m, o));
    if ((t & 63) == 0) red[t >> 6] = m;
    __syncthreads();
    m = fmaxf(fmaxf(red[0], red[1]), fmaxf(red[2], red[3]));
    __syncthreads();
    float p = (t < n) ? expf(e - m) : 0.f;
    float s = p;
    for (int o = 32; o; o >>= 1) s += __shfl_xor(s, o);
    if ((t & 63) == 0) red[t >> 6] = s;
    __syncthreads();
    s = red[0] + red[1] + red[2] + red[3];
    if (t < n) sa[t] = p / s;
    __syncthreads();
    int cd = br ? 512 : 0;
    for (int k = w; k < n; k += 4) {
      ushort4 y = *(const ushort4*)(Y + (size_t)sj[k] * 1280 + cd + 4 * l);
      float a = sa[k];
      acc.x += a * bf2f(y.x); acc.y += a * bf2f(y.y);
      acc.z += a * bf2f(y.z); acc.w += a * bf2f(y.w);
    }
    __syncthreads();
  }

  {
    size_t rbase = ((size_t)2 * NROW + row) * MAXNNZ;
    int n = cnt[2 * NROW + row];
    if (t < n) { sj[t] = idx[rbase + t]; sa[t] = val[rbase + t]; }
    __syncthreads();
    for (int k = w; k < n; k += 4) {
      ushort4 y = *(const ushort4*)(Y + (size_t)sj[k] * 1280 + 1024 + 4 * l);
      float a = sa[k];
      acc.x += a * bf2f(y.x); acc.y += a * bf2f(y.y);
      acc.z += a * bf2f(y.z); acc.w += a * bf2f(y.w);
    }
  }
  ((float4*)part[w])[l] = acc;
  __syncthreads();
  if (t < 64) {
    float4 r;
    int c = 4 * t;
    r.x = part[0][c]     + part[1][c]     + part[2][c]     + part[3][c]     + bi[c]     + bi[256 + c] + bs[c]     + bs[256 + c] + bh[c];
    r.y = part[0][c + 1] + part[1][c + 1] + part[2][c + 1] + part[3][c + 1] + bi[c + 1] + bi[257 + c] + bs[c + 1] + bs[257 + c] + bh[c + 1];
    r.z = part[0][c + 2] + part[1][c + 2] + part[2][c + 2] + part[3][c + 2] + bi[c + 2] + bi[258 + c] + bs[c + 2] + bs[258 + c] + bh[c + 2];
    r.w = part[0][c + 3] + part[1][c + 3] + part[2][c + 3] + part[3][c + 3] + bi[c + 3] + bi[259 + c] + bs[c + 3] + bs[259 + c] + bh[c + 3];
    *(float4*)(Z + (size_t)row * 256 + c) = r;
  }
}

// ---------------------------------------------------------------------------
extern "C" void kernel_launch(void* const* d_in, const int* in_sizes, int n_in,
                              void* d_out, int out_size, void* d_ws, size_t ws_size,
                              hipStream_t stream) {
  const float* x      = (const float*)d_in[0];
  const float* Lup    = (const float*)d_in[1];
  const float* Ld     = (const float*)d_in[2];
  const float* P      = (const float*)d_in[3];
  const float* Wirr_w = (const float*)d_in[4];
  const float* Wirr_b = (const float*)d_in[5];
  const float* Wsol_w = (const float*)d_in[6];
  const float* Wsol_b = (const float*)d_in[7];
  const float* Whar_w = (const float*)d_in[8];
  const float* Whar_b = (const float*)d_in[9];
  const float* att_i  = (const float*)d_in[10];
  const float* att_s  = (const float*)d_in[11];
  float* Z = (float*)d_out;

  char* w = (char*)d_ws;
  auto alloc = [&](size_t bytes) { void* p = (void*)w; w += (bytes + 255) & ~(size_t)255; return p; };

  int*   idx  = (int*)alloc((size_t)3 * NROW * MAXNNZ * 4);
  float* val  = (float*)alloc((size_t)3 * NROW * MAXNNZ * 4);
  int*   cnt  = (int*)alloc((size_t)3 * NROW * 4);
  float* sdv  = (float*)alloc(4 * NROW * 4);
  unsigned short* xbf = (unsigned short*)alloc((size_t)NROW * CH * 2);
  unsigned short* Bbf = (unsigned short*)alloc((size_t)1280 * CH * 2);
  unsigned short* Y   = (unsigned short*)alloc((size_t)NROW * 1280 * 2);

  // mat slot order: 0 = Ld (irr), 1 = Lup (sol), 2 = P
  scan_nt<<<3 * NROW, 256, 0, stream>>>(Ld, Lup, P, idx, val, cnt);

  // buffer window between HBM burst and cache-sensitive tail:
  cvt_all<<<(262144 + 32768 + 32768 + 16384) / 256, 256, 0, stream>>>(x, Wirr_w, Wsol_w, Whar_w, xbf, Bbf);
  gemm_mfma<<<1280, 256, 0, stream>>>(xbf, Bbf, Y);

  spmm_sdv<<<NROW, 256, 0, stream>>>(idx, val, cnt, att_i, att_s, Wirr_b, Wsol_b, Y, sdv);

  final_z<<<NROW, 256, 0, stream>>>(idx, val, cnt, sdv, Y, Wirr_b, Wsol_b, Whar_b, Z);
}

// Round 16
// 108.332 us; speedup vs baseline: 1.0608x; 1.0608x over previous
//
#include <hip/hip_runtime.h>

#define NROW 4096
#define CH   256
#define MAXNNZ 128

typedef short  short8  __attribute__((ext_vector_type(8)));
typedef unsigned short ushort8 __attribute__((ext_vector_type(8)));
typedef float  f32x4   __attribute__((ext_vector_type(4)));

__device__ inline unsigned short f2bf(float f) {
  unsigned u = __float_as_uint(f);
  return (unsigned short)((u + 0x7fffu + ((u >> 16) & 1u)) >> 16);
}
__device__ inline float bf2f(unsigned short h) {
  return __uint_as_float((unsigned)h << 16);
}
__device__ inline int mbcnt64(unsigned long long m, int base) {
  int t = __builtin_amdgcn_mbcnt_lo((unsigned)m, (unsigned)base);
  return __builtin_amdgcn_mbcnt_hi((unsigned)(m >> 32), t);
}

// ---------------------------------------------------------------------------
// One dispatch converting x, Wirr_w, Wsol_w, Whar_w to bf16 (4 f32/thread).
__global__ void cvt_all(const float* __restrict__ x, const float* __restrict__ Wi,
                        const float* __restrict__ Ws, const float* __restrict__ Wh,
                        unsigned short* __restrict__ xbf, unsigned short* __restrict__ Bbf) {
  int i = blockIdx.x * 256 + threadIdx.x;       // float4 index
  const float* src; unsigned short* dst; int o;
  if (i < 262144)        { src = x;  dst = xbf;          o = i; }
  else if (i < 294912)   { src = Wi; dst = Bbf;          o = i - 262144; }
  else if (i < 327680)   { src = Ws; dst = Bbf + 131072; o = i - 294912; }
  else                   { src = Wh; dst = Bbf + 262144; o = i - 327680; }
  float4 v = ((const float4*)src)[o];
  ushort4 u;
  u.x = f2bf(v.x); u.y = f2bf(v.y); u.z = f2bf(v.z); u.w = f2bf(v.w);
  ((ushort4*)dst)[o] = u;
}

// ---------------------------------------------------------------------------
// R9 configuration (best: 107.8us) with ONE change: the scan's L-loads use
// device-scope `sc1` (inline asm) = bypass the per-XCD L2 but still allocate
// in the memory-side L3. Rationale: R12/R14 showed the scan wall is L2
// allocation machinery (nt @HBM 2.7TB/s beats cached @L3 1.5TB/s), but nt
// also kills L3 residency, which the tail + warm replays pay for. sc1 aims
// at nt's speed with L3 retention, and keeps L2 exclusively for Y/CSR.
__global__ __launch_bounds__(256) void scan_gemm(
    const float* __restrict__ L0, const float* __restrict__ L1,
    const float* __restrict__ L2, int* __restrict__ idx,
    float* __restrict__ val, int* __restrict__ cnt,
    const unsigned short* __restrict__ A, const unsigned short* __restrict__ Bt,
    unsigned short* __restrict__ Y) {
  __shared__ __align__(16) union {
    struct { unsigned short sA[64 * 128]; unsigned short sB[64 * 128]; } g;   // 32 KB
    struct { int sj[4][MAXNNZ]; float sv[4][MAXNNZ]; int scnt[4]; } c;        // 4.1 KB
  } u;
  const int bid = blockIdx.x, tid = threadIdx.x;
  const bool is_gemm = (bid < 12800) && (bid % 10 == 9);

  if (is_gemm) {
    const int gid = bid / 10;
    const int m0 = (gid & 63) * 64, n0 = (gid >> 6) * 64;
    const int wid = tid >> 6, lane = tid & 63;
    const int wr = wid >> 1, wc = wid & 1, lr = lane & 15, kg = lane >> 4;
    f32x4 acc[2][2] = {};
#pragma unroll
    for (int kh = 0; kh < 2; ++kh) {
      for (int c = 0; c < 4; ++c) {
        int chunk = c * 256 + tid;          // 0..1023
        int r  = chunk >> 4;                // 16 chunks per 256B row
        int cb = (chunk & 15) * 16;
        int cbs = cb ^ ((r & 7) << 4);
        ushort8 va = *(const ushort8*)((const char*)A  + (size_t)(m0 + r) * 512 + kh * 256 + cb);
        *(ushort8*)((char*)u.g.sA + r * 256 + cbs) = va;
        ushort8 vb = *(const ushort8*)((const char*)Bt + (size_t)(n0 + r) * 512 + kh * 256 + cb);
        *(ushort8*)((char*)u.g.sB + r * 256 + cbs) = vb;
      }
      __syncthreads();
#pragma unroll
      for (int ks = 0; ks < 4; ++ks) {
        int kb = ks * 64 + kg * 16;
        short8 a0, a1, b0, b1;
        { int r = wr * 32 + lr;      a0 = *(const short8*)((const char*)u.g.sA + r * 256 + (kb ^ ((r & 7) << 4))); }
        { int r = wr * 32 + 16 + lr; a1 = *(const short8*)((const char*)u.g.sA + r * 256 + (kb ^ ((r & 7) << 4))); }
        { int r = wc * 32 + lr;      b0 = *(const short8*)((const char*)u.g.sB + r * 256 + (kb ^ ((r & 7) << 4))); }
        { int r = wc * 32 + 16 + lr; b1 = *(const short8*)((const char*)u.g.sB + r * 256 + (kb ^ ((r & 7) << 4))); }
        acc[0][0] = __builtin_amdgcn_mfma_f32_16x16x32_bf16(a0, b0, acc[0][0], 0, 0, 0);
        acc[0][1] = __builtin_amdgcn_mfma_f32_16x16x32_bf16(a0, b1, acc[0][1], 0, 0, 0);
        acc[1][0] = __builtin_amdgcn_mfma_f32_16x16x32_bf16(a1, b0, acc[1][0], 0, 0, 0);
        acc[1][1] = __builtin_amdgcn_mfma_f32_16x16x32_bf16(a1, b1, acc[1][1], 0, 0, 0);
      }
      __syncthreads();
    }
#pragma unroll
    for (int mi = 0; mi < 2; ++mi)
#pragma unroll
      for (int ni = 0; ni < 2; ++ni) {
        int col = n0 + wc * 32 + ni * 16 + lr;
#pragma unroll
        for (int r4 = 0; r4 < 4; ++r4) {
          int row = m0 + wr * 32 + mi * 16 + kg * 4 + r4;
          Y[(size_t)row * 1280 + col] = f2bf(acc[mi][ni][r4]);
        }
      }
  } else {
    const int cid = (bid < 12800) ? (bid - (bid + 1) / 10) : (bid - 1280);
    const int mat = cid >> 12, row = cid & 4095;
    const float* L = (mat == 0) ? L0 : (mat == 1) ? L1 : L2;
    const int wi = tid >> 6, lane = tid & 63;
    const char* pb = (const char*)(L + (size_t)row * NROW) + wi * 4096 + lane * 16;

    f32x4 v0, v1, v2, v3;
    asm volatile(
        "global_load_dwordx4 %[d0], %[a], off sc1\n\t"
        "global_load_dwordx4 %[d1], %[a], off offset:1024 sc1\n\t"
        "global_load_dwordx4 %[d2], %[a], off offset:2048 sc1\n\t"
        "global_load_dwordx4 %[d3], %[a], off offset:3072 sc1\n\t"
        "s_waitcnt vmcnt(0)"
        : [d0] "=&v"(v0), [d1] "=&v"(v1), [d2] "=&v"(v2), [d3] "=&v"(v3)
        : [a] "v"(pb)
        : "memory");

    int base = 0;
#define PROCQ(q, cb) {                                                          \
    bool a0 = q[0] != 0.f, a1 = q[1] != 0.f, a2 = q[2] != 0.f, a3 = q[3] != 0.f; \
    unsigned long long b0 = __ballot(a0), b1 = __ballot(a1);                    \
    unsigned long long b2 = __ballot(a2), b3 = __ballot(a3);                    \
    int off = mbcnt64(b3, mbcnt64(b2, mbcnt64(b1, mbcnt64(b0, base))));         \
    if (a0) { if (off < MAXNNZ) { u.c.sj[wi][off] = (cb);     u.c.sv[wi][off] = q[0]; } ++off; } \
    if (a1) { if (off < MAXNNZ) { u.c.sj[wi][off] = (cb) + 1; u.c.sv[wi][off] = q[1]; } ++off; } \
    if (a2) { if (off < MAXNNZ) { u.c.sj[wi][off] = (cb) + 2; u.c.sv[wi][off] = q[2]; } ++off; } \
    if (a3) { if (off < MAXNNZ) { u.c.sj[wi][off] = (cb) + 3; u.c.sv[wi][off] = q[3]; } ++off; } \
    base += __popcll(b0) + __popcll(b1) + __popcll(b2) + __popcll(b3); }
    int colb = wi * 1024 + lane * 4;
    PROCQ(v0, colb)
    PROCQ(v1, colb + 256)
    PROCQ(v2, colb + 512)
    PROCQ(v3, colb + 768)
#undef PROCQ
    if (lane == 0) u.c.scnt[wi] = base < MAXNNZ ? base : MAXNNZ;
    __syncthreads();

    int c0 = u.c.scnt[0], c1 = u.c.scnt[1], c2 = u.c.scnt[2], c3 = u.c.scnt[3];
    int total = c0 + c1 + c2 + c3;
    if (total > MAXNNZ) total = MAXNNZ;
    size_t rbase = ((size_t)mat * NROW + row) * MAXNNZ;
    int t = tid;
    if (t < total) {
      int s, o;
      if      (t < c0)           { s = 0; o = t; }
      else if (t < c0 + c1)      { s = 1; o = t - c0; }
      else if (t < c0 + c1 + c2) { s = 2; o = t - c0 - c1; }
      else                       { s = 3; o = t - c0 - c1 - c2; }
      idx[rbase + t] = u.c.sj[s][o];
      val[rbase + t] = u.c.sv[s][o];
    }
    if (t == 0) cnt[mat * NROW + row] = total;
  }
}

// ---------------------------------------------------------------------------
// MERGED per-row kernel: sdv (att-dots on own row's Y[0..1023]) + BOTH
// spmm_add branches (U_d -> cols 0-255, U_s -> cols 512-767). Gathers read
// only cols 256-511 / 768-1023 (never written) -> no cross-block race.
__global__ __launch_bounds__(256) void spmm_sdv(
    const int* __restrict__ idx, const float* __restrict__ val,
    const int* __restrict__ cnt, const float* __restrict__ ai,
    const float* __restrict__ as_, const float* __restrict__ bi,
    const float* __restrict__ bs, unsigned short* __restrict__ Y,
    float* __restrict__ sdv) {
  int row = blockIdx.x, t = threadIdx.x, w = t >> 6, l = t & 63;
  __shared__ float satt[2048];
  __shared__ float red2[8];
  __shared__ float sbias[4];
  __shared__ int   sj0[MAXNNZ], sj1[MAXNNZ];
  __shared__ float sv0[MAXNNZ], sv1[MAXNNZ];
  __shared__ float part[4][256];

  for (int k = t; k < 1024; k += 256) { satt[k] = ai[k]; satt[1024 + k] = as_[k]; }
  {
    const float* av = (w & 2) ? as_ : ai;
    const float* bv = (w & 2) ? bs : bi;
    int off = (w & 1) * 512;
    float b = 0.f;
    for (int k = l; k < 512; k += 64) b += av[off + k] * bv[k];
    for (int o = 32; o; o >>= 1) b += __shfl_xor(b, o);
    if (l == 0) sbias[w] = b;
  }
  int n0 = cnt[row], n1 = cnt[NROW + row];
  if (t < n0) { sj0[t] = idx[(size_t)row * MAXNNZ + t];          sv0[t] = val[(size_t)row * MAXNNZ + t]; }
  if (t < n1) { sj1[t] = idx[((size_t)NROW + row) * MAXNNZ + t]; sv1[t] = val[((size_t)NROW + row) * MAXNNZ + t]; }
  ushort4 y4 = *(const ushort4*)(Y + (size_t)row * 1280 + 4 * t);   // own row, pre-overwrite
  __syncthreads();

  {
    int c0 = 4 * t;
    int aoff = (t < 128) ? 0 : 1024;
    int cc = c0 & 511;
    float sp = satt[aoff + cc]       * bf2f(y4.x) + satt[aoff + cc + 1]       * bf2f(y4.y)
             + satt[aoff + cc + 2]   * bf2f(y4.z) + satt[aoff + cc + 3]       * bf2f(y4.w);
    float dp = satt[aoff + 512 + cc] * bf2f(y4.x) + satt[aoff + 512 + cc + 1] * bf2f(y4.y)
             + satt[aoff + 512 + cc + 2] * bf2f(y4.z) + satt[aoff + 512 + cc + 3] * bf2f(y4.w);
    for (int o = 32; o; o >>= 1) { sp += __shfl_xor(sp, o); dp += __shfl_xor(dp, o); }
    if (l == 0) { red2[w * 2] = sp; red2[w * 2 + 1] = dp; }
  }

  float4 acc0 = {0.f, 0.f, 0.f, 0.f}, acc1 = {0.f, 0.f, 0.f, 0.f};
  for (int k = w; k < n0; k += 4) {
    ushort4 y = *(const ushort4*)(Y + (size_t)sj0[k] * 1280 + 256 + 4 * l);
    float a = sv0[k];
    acc0.x += a * bf2f(y.x); acc0.y += a * bf2f(y.y);
    acc0.z += a * bf2f(y.z); acc0.w += a * bf2f(y.w);
  }
  for (int k = w; k < n1; k += 4) {
    ushort4 y = *(const ushort4*)(Y + (size_t)sj1[k] * 1280 + 768 + 4 * l);
    float a = sv1[k];
    acc1.x += a * bf2f(y.x); acc1.y += a * bf2f(y.y);
    acc1.z += a * bf2f(y.z); acc1.w += a * bf2f(y.w);
  }
  ((float4*)part[w])[l] = acc0;
  __syncthreads();
  if (t == 0) {
    sdv[row]            = red2[0] + red2[2] + sbias[0];
    sdv[NROW + row]     = red2[1] + red2[3] + sbias[1];
    sdv[2 * NROW + row] = red2[4] + red2[6] + sbias[2];
    sdv[3 * NROW + row] = red2[5] + red2[7] + sbias[3];
  }
  if (t < 64) {
    unsigned short* yp = Y + (size_t)row * 1280 + 4 * t;
    ushort4 yb = *(const ushort4*)yp;
    ushort4 o;
    o.x = f2bf(bf2f(yb.x) + part[0][4 * t]     + part[1][4 * t]     + part[2][4 * t]     + part[3][4 * t]);
    o.y = f2bf(bf2f(yb.y) + part[0][4 * t + 1] + part[1][4 * t + 1] + part[2][4 * t + 1] + part[3][4 * t + 1]);
    o.z = f2bf(bf2f(yb.z) + part[0][4 * t + 2] + part[1][4 * t + 2] + part[2][4 * t + 2] + part[3][4 * t + 2]);
    o.w = f2bf(bf2f(yb.w) + part[0][4 * t + 3] + part[1][4 * t + 3] + part[2][4 * t + 3] + part[3][4 * t + 3]);
    *(ushort4*)yp = o;
  }
  __syncthreads();
  ((float4*)part[w])[l] = acc1;
  __syncthreads();
  if (t < 64) {
    unsigned short* yp = Y + (size_t)row * 1280 + 512 + 4 * t;
    ushort4 yb = *(const ushort4*)yp;
    ushort4 o;
    o.x = f2bf(bf2f(yb.x) + part[0][4 * t]     + part[1][4 * t]     + part[2][4 * t]     + part[3][4 * t]);
    o.y = f2bf(bf2f(yb.y) + part[0][4 * t + 1] + part[1][4 * t + 1] + part[2][4 * t + 1] + part[3][4 * t + 1]);
    o.z = f2bf(bf2f(yb.z) + part[0][4 * t + 2] + part[1][4 * t + 2] + part[2][4 * t + 2] + part[3][4 * t + 2]);
    o.w = f2bf(bf2f(yb.w) + part[0][4 * t + 3] + part[1][4 * t + 3] + part[2][4 * t + 3] + part[3][4 * t + 3]);
    *(ushort4*)yp = o;
  }
}

// ---------------------------------------------------------------------------
// Z[row] = alpha_d @ U_d + alpha_s @ U_s + P @ Yh + (all biases)
__global__ __launch_bounds__(256) void final_z(const int* __restrict__ idx,
                        const float* __restrict__ val, const int* __restrict__ cnt,
                        const float* __restrict__ sdv,
                        const unsigned short* __restrict__ Y,
                        const float* __restrict__ bi, const float* __restrict__ bs,
                        const float* __restrict__ bh, float* __restrict__ Z) {
  int row = blockIdx.x, t = threadIdx.x, w = t >> 6, l = t & 63;
  __shared__ float sa[MAXNNZ];
  __shared__ int   sj[MAXNNZ];
  __shared__ float red[4];
  __shared__ float part[4][256];
  float4 acc = {0.f, 0.f, 0.f, 0.f};

  for (int br = 0; br < 2; ++br) {
    size_t rbase = ((size_t)br * NROW + row) * MAXNNZ;
    int n = cnt[br * NROW + row];
    const float* srcv = sdv + (2 * br) * NROW;
    const float* dstv = sdv + (2 * br + 1) * NROW;
    float e = -1e30f;
    if (t < n) {
      int j = idx[rbase + t];
      sj[t] = j;
      float v = srcv[row] + dstv[j];
      e = v >= 0.f ? v : 0.01f * v;
    }
    float m = e;
    for (int o = 32; o; o >>= 1) m = fmaxf(m, __shfl_xor(m, o));
    if ((t & 63) == 0) red[t >> 6] = m;
    __syncthreads();
    m = fmaxf(fmaxf(red[0], red[1]), fmaxf(red[2], red[3]));
    __syncthreads();
    float p = (t < n) ? expf(e - m) : 0.f;
    float s = p;
    for (int o = 32; o; o >>= 1) s += __shfl_xor(s, o);
    if ((t & 63) == 0) red[t >> 6] = s;
    __syncthreads();
    s = red[0] + red[1] + red[2] + red[3];
    if (t < n) sa[t] = p / s;
    __syncthreads();
    int cd = br ? 512 : 0;
    for (int k = w; k < n; k += 4) {
      ushort4 y = *(const ushort4*)(Y + (size_t)sj[k] * 1280 + cd + 4 * l);
      float a = sa[k];
      acc.x += a * bf2f(y.x); acc.y += a * bf2f(y.y);
      acc.z += a * bf2f(y.z); acc.w += a * bf2f(y.w);
    }
    __syncthreads();
  }

  {
    size_t rbase = ((size_t)2 * NROW + row) * MAXNNZ;
    int n = cnt[2 * NROW + row];
    if (t < n) { sj[t] = idx[rbase + t]; sa[t] = val[rbase + t]; }
    __syncthreads();
    for (int k = w; k < n; k += 4) {
      ushort4 y = *(const ushort4*)(Y + (size_t)sj[k] * 1280 + 1024 + 4 * l);
      float a = sa[k];
      acc.x += a * bf2f(y.x); acc.y += a * bf2f(y.y);
      acc.z += a * bf2f(y.z); acc.w += a * bf2f(y.w);
    }
  }
  ((float4*)part[w])[l] = acc;
  __syncthreads();
  if (t < 64) {
    float4 r;
    int c = 4 * t;
    r.x = part[0][c]     + part[1][c]     + part[2][c]     + part[3][c]     + bi[c]     + bi[256 + c] + bs[c]     + bs[256 + c] + bh[c];
    r.y = part[0][c + 1] + part[1][c + 1] + part[2][c + 1] + part[3][c + 1] + bi[c + 1] + bi[257 + c] + bs[c + 1] + bs[257 + c] + bh[c + 1];
    r.z = part[0][c + 2] + part[1][c + 2] + part[2][c + 2] + part[3][c + 2] + bi[c + 2] + bi[258 + c] + bs[c + 2] + bs[258 + c] + bh[c + 2];
    r.w = part[0][c + 3] + part[1][c + 3] + part[2][c + 3] + part[3][c + 3] + bi[c + 3] + bi[259 + c] + bs[c + 3] + bs[259 + c] + bh[c + 3];
    *(float4*)(Z + (size_t)row * 256 + c) = r;
  }
}

// ---------------------------------------------------------------------------
extern "C" void kernel_launch(void* const* d_in, const int* in_sizes, int n_in,
                              void* d_out, int out_size, void* d_ws, size_t ws_size,
                              hipStream_t stream) {
  const float* x      = (const float*)d_in[0];
  const float* Lup    = (const float*)d_in[1];
  const float* Ld     = (const float*)d_in[2];
  const float* P      = (const float*)d_in[3];
  const float* Wirr_w = (const float*)d_in[4];
  const float* Wirr_b = (const float*)d_in[5];
  const float* Wsol_w = (const float*)d_in[6];
  const float* Wsol_b = (const float*)d_in[7];
  const float* Whar_w = (const float*)d_in[8];
  const float* Whar_b = (const float*)d_in[9];
  const float* att_i  = (const float*)d_in[10];
  const float* att_s  = (const float*)d_in[11];
  float* Z = (float*)d_out;

  char* w = (char*)d_ws;
  auto alloc = [&](size_t bytes) { void* p = (void*)w; w += (bytes + 255) & ~(size_t)255; return p; };

  int*   idx  = (int*)alloc((size_t)3 * NROW * MAXNNZ * 4);
  float* val  = (float*)alloc((size_t)3 * NROW * MAXNNZ * 4);
  int*   cnt  = (int*)alloc((size_t)3 * NROW * 4);
  float* sdv  = (float*)alloc(4 * NROW * 4);
  unsigned short* xbf = (unsigned short*)alloc((size_t)NROW * CH * 2);
  unsigned short* Bbf = (unsigned short*)alloc((size_t)1280 * CH * 2);
  unsigned short* Y   = (unsigned short*)alloc((size_t)NROW * 1280 * 2);

  cvt_all<<<(262144 + 32768 + 32768 + 16384) / 256, 256, 0, stream>>>(x, Wirr_w, Wsol_w, Whar_w, xbf, Bbf);

  // mat slot order: 0 = Ld (irr), 1 = Lup (sol), 2 = P
  scan_gemm<<<13568, 256, 0, stream>>>(Ld, Lup, P, idx, val, cnt, xbf, Bbf, Y);

  spmm_sdv<<<NROW, 256, 0, stream>>>(idx, val, cnt, att_i, att_s, Wirr_b, Wsol_b, Y, sdv);

  final_z<<<NROW, 256, 0, stream>>>(idx, val, cnt, sdv, Y, Wirr_b, Wsol_b, Whar_b, Z);
}